// Round 7
// baseline (212.676 us; speedup 1.0000x reference)
//
#include <hip/hip_runtime.h>
#include <math.h>

// Problem constants
#define B 8192
#define E 1024
#define D 384
#define H 64
#define R 8
#define NCHUNK 16
#define CHUNK_E 64
#define NPOS 16448   // 16384 + per-router pad-to-8

// ws byte offsets (total 7,623,168 B)
#define WS_COUNTS   0u
#define WS_CURSORS  32u
#define WS_PS       64u
#define WS_TOP2     256u      // int2[B]      -> 65792
#define WS_GW       65792u    // float2[B]    -> 131328
#define WS_POSMAP   131328u   // int2[B]      -> 196864
#define WS_LIST     196864u   // int[NPOS]    -> 262656
#define WS_EVN      262656u   // float[R*64*1024] evnT[r][h][e] -> 2359808
#define WS_XUN      2359808u  // float[NPOS*H]    xunP[pos][h]  -> 6570496
#define WS_C        6570496u  // float[NPOS*16]   C[pos][chunk] -> 7623168

// ---------------- gate: lane = (sample, router); LDS-transposed gate_w -----
__global__ __launch_bounds__(256) void k_gate(
    const float* __restrict__ x, const float* __restrict__ gate_w,
    const float* __restrict__ gate_b, int2* __restrict__ top2,
    float2* __restrict__ gwv, int* __restrict__ counts, float* __restrict__ ps)
{
  __shared__ __align__(16) float gwT[R * 388];
  __shared__ float psl[R];
  __shared__ int   cl[R];
  int tid = threadIdx.x;
  for (int idx = tid; idx < D * R; idx += 256) {
    int k = idx >> 3, r = idx & 7;
    gwT[r * 388 + k] = gate_w[idx];
  }
  if (tid < R) { psl[tid] = 0.f; cl[tid] = 0; }
  __syncthreads();

  int l = tid & 63;
  int r = tid & 7;
  int b = blockIdx.x * 32 + (tid >> 3);
  float acc = gate_b[r];
  const float4* x4 = (const float4*)(x + (size_t)b * D);
  const float*  gr = gwT + r * 388;
#pragma unroll 4
  for (int q = 0; q < 96; ++q) {
    float4 xv = x4[q];
    float4 gv = *(const float4*)&gr[q * 4];
    acc = fmaf(xv.x, gv.x, acc);
    acc = fmaf(xv.y, gv.y, acc);
    acc = fmaf(xv.z, gv.z, acc);
    acc = fmaf(xv.w, gv.w, acc);
  }
  float lv[R];
#pragma unroll
  for (int rr = 0; rr < R; ++rr) lv[rr] = __shfl(acc, (l & ~7) + rr);
  int i0 = 0; float v0 = lv[0];
#pragma unroll
  for (int rr = 1; rr < R; ++rr) if (lv[rr] > v0) { v0 = lv[rr]; i0 = rr; }
  int i1 = (i0 == 0) ? 1 : 0; float v1 = lv[i1];
#pragma unroll
  for (int rr = 0; rr < R; ++rr)
    if (rr != i0 && lv[rr] > v1) { v1 = lv[rr]; i1 = rr; }
  float se = 0.f;
#pragma unroll
  for (int rr = 0; rr < R; ++rr) se += expf(lv[rr] - v0);
  float p = expf(acc - v0) / se;
  if (r == 0) {
    float e10 = expf(v1 - v0);
    top2[b] = make_int2(i0, i1);
    gwv[b]  = make_float2(1.f / (1.f + e10), e10 / (1.f + e10));
  }
  float pa = p;
  int   ca = (r == i0 ? 1 : 0) + (r == i1 ? 1 : 0);
#pragma unroll
  for (int m = 8; m < 64; m <<= 1) {
    pa += __shfl_xor(pa, m);
    ca += __shfl_xor(ca, m);
  }
  if (l < 8) { atomicAdd(&psl[r], pa); atomicAdd(&cl[r], ca); }
  __syncthreads();
  if (tid < R) { atomicAdd(&ps[tid], psl[tid]); atomicAdd(&counts[tid], cl[tid]); }
}

// ---------------- scatter: per-router lists (padded-to-8 bases) + aux ------
__global__ __launch_bounds__(256) void k_scatter(
    const int2* __restrict__ top2, const int* __restrict__ counts,
    const float* __restrict__ ps, int* __restrict__ cursors,
    int* __restrict__ list, int2* __restrict__ posmap, float* __restrict__ out_aux)
{
  __shared__ int lc[R];
  __shared__ int lbase[R];
  __shared__ int offs[R];
  int tid = threadIdx.x;
  if (tid < R) lc[tid] = 0;
  __syncthreads();
  if (tid == 0) {
    int o = 0;
    for (int r2 = 0; r2 < R; ++r2) { offs[r2] = o; o += (min(counts[r2], B) + 7) & ~7; }
  }
  __syncthreads();
  int b = min(blockIdx.x * 256 + tid, B - 1);
  int2 t = top2[b];
  t.x &= 7; t.y &= 7;
  int p0 = atomicAdd(&lc[t.x], 1);
  int p1 = atomicAdd(&lc[t.y], 1);
  __syncthreads();
  if (tid < R) lbase[tid] = atomicAdd(&cursors[tid], lc[tid]);
  __syncthreads();
  int i0 = min(offs[t.x] + lbase[t.x] + p0, NPOS - 1);
  int i1 = min(offs[t.y] + lbase[t.y] + p1, NPOS - 1);
  list[i0] = b * 2 + 0;
  list[i1] = b * 2 + 1;
  posmap[b] = make_int2(i0, i1);
  if (blockIdx.x == 0 && tid == 0) {
    float s = 0.f;
    for (int r2 = 0; r2 < R; ++r2)
      s += (ps[r2] / (float)B) * ((float)min(counts[r2], B) / (float)B);
    out_aux[0] = (float)R * s * 0.05f;
  }
}

// ---------------- proj: register-GEMM, zero LDS ----------------------------
// wave = 64 h-lanes; 8 rows/wave; K in 6 register chunks of 64 (w[64] VGPRs).
// Per MAC-group: 1 v_readlane (x scalar) + 1 v_fmac across 64 h.
// grid: bid<256 evn (r=bid>>5, g=bid&31); else xun (r=(bid-256)>>8, g=&255).
__global__ __launch_bounds__(256) void k_proj(
    const float* __restrict__ re, const float* __restrict__ x,
    const float* __restrict__ Vw, const float* __restrict__ Vb,
    const float* __restrict__ Uw, const float* __restrict__ Ub,
    const int* __restrict__ list, const int* __restrict__ counts,
    float* __restrict__ evnT, float* __restrict__ xunP)
{
  int tid = threadIdx.x;
  int lane = tid & 63;
  int wv = tid >> 6;
  int bid = blockIdx.x;

  bool isE = (bid < 256);
  int r, g, n = 32, base = 0;
  const float *W, *bias;
  if (isE) {
    r = bid >> 5; g = bid & 31;
    W = Vw + (size_t)r * (D * H); bias = Vb + r * H;
  } else {
    int idx = bid - 256;
    r = idx >> 8; g = idx & 255;
    int cnt = min(counts[r], B);
    if (g * 32 >= cnt) return;
    n = min(32, cnt - g * 32);
    for (int rr = 0; rr < r; ++rr) base += (min(counts[rr], B) + 7) & ~7;
    base += g * 32;
    W = Uw + (size_t)r * (D * H); bias = Ub + r * H;
  }
  int row0 = wv * 8;
  if (row0 >= n) return;

  const float* arow[8];
#pragma unroll
  for (int i = 0; i < 8; ++i) {
    int rr = min(row0 + i, n - 1);
    if (isE) {
      arow[i] = re + (size_t)(g * 32 + rr) * D;
    } else {
      int gl = list[min(base + rr, NPOS - 1)];
      gl = min(max(gl, 0), 2 * B - 1);
      arow[i] = x + (size_t)(gl >> 1) * D;
    }
  }
  float bv = bias[lane];
  float acc[8];
#pragma unroll
  for (int i = 0; i < 8; ++i) acc[i] = bv;

  for (int c = 0; c < 6; ++c) {
    float w[64];
#pragma unroll
    for (int k = 0; k < 64; ++k) w[k] = W[(size_t)(c * 64 + k) * H + lane];
    float xa[8];
#pragma unroll
    for (int i = 0; i < 8; ++i) xa[i] = arow[i][c * 64 + lane];
#pragma unroll
    for (int k = 0; k < 64; ++k) {   // full unroll: w[k] const-indexed, readlane const
      float wk = w[k];
#pragma unroll
      for (int i = 0; i < 8; ++i) {
        float s = __uint_as_float(__builtin_amdgcn_readlane(__float_as_uint(xa[i]), k));
        acc[i] = fmaf(s, wk, acc[i]);
      }
    }
  }

  float rn[8];
#pragma unroll
  for (int i = 0; i < 8; ++i) {
    float ss = acc[i] * acc[i];
#pragma unroll
    for (int m = 1; m < 64; m <<= 1) ss += __shfl_xor(ss, m);
    rn[i] = 1.f / fmaxf(sqrtf(ss), 1e-12f);
  }

  if (isE) {
    int e0 = g * 32 + row0;
    float4 o0, o1;
    o0.x = acc[0] * rn[0]; o0.y = acc[1] * rn[1];
    o0.z = acc[2] * rn[2]; o0.w = acc[3] * rn[3];
    o1.x = acc[4] * rn[4]; o1.y = acc[5] * rn[5];
    o1.z = acc[6] * rn[6]; o1.w = acc[7] * rn[7];
    float* dst = evnT + (size_t)(r * 64 + lane) * 1024 + e0;
    *(float4*)dst = o0;
    *(float4*)(dst + 4) = o1;
  } else {
#pragma unroll
    for (int i = 0; i < 8; ++i)
      if (row0 + i < n)
        xunP[(size_t)(base + row0 + i) * H + lane] = acc[i] * rn[i];
  }
}

// ---------------- pass1: scores GEMM -> exp -> chunk sums ------------------
// tile 128 pos x 128 e (2 chunks); 8x8/thread; LDS Xt[k][s] 32KB + Et[k][e]
// 32KB; hot loop 4x ds_read_b128 (<=2-way banks) + 64 FMA per k-step.
__global__ __launch_bounds__(256) void k_pass1(
    const float* __restrict__ evnT, const float* __restrict__ xunP,
    const int* __restrict__ counts, float* __restrict__ C)
{
  __shared__ __align__(16) float Xt[64 * 128];
  __shared__ __align__(16) float Et[64 * 128];
  __shared__ int cntL[R];
  int tid = threadIdx.x;
  if (tid < R) cntL[tid] = min(counts[tid], B);
  __syncthreads();

  int bid = blockIdx.x;
  int et    = bid & 7;
  int stile = (bid >> 3) & 63;
  int r     = bid >> 9;
  int cnt = cntL[r];
  if (cnt <= 0 || stile * 128 >= cnt) return;
  int off = 0;
  for (int rr = 0; rr < r; ++rr) off += (cntL[rr] + 7) & ~7;
  off += stile * 128;
  int n = min(128, cnt - stile * 128);
  int ebase = et * 128;

  {  // Xt: transpose-stage xunP rows [pos][h] -> [h][s]
    int row = tid >> 1;
    int rc  = min(row, n - 1);
    const float4* src = (const float4*)(xunP + (size_t)(off + rc) * H);
    int hq0 = (tid & 1) * 8;
#pragma unroll
    for (int q = 0; q < 8; ++q) {
      float4 v = src[hq0 + q];
      int h = (hq0 + q) * 4;
      Xt[(h + 0) * 128 + row] = v.x;
      Xt[(h + 1) * 128 + row] = v.y;
      Xt[(h + 2) * 128 + row] = v.z;
      Xt[(h + 3) * 128 + row] = v.w;
    }
  }
  {  // Et: direct copy of evnT [h][ebase..ebase+128)
#pragma unroll
    for (int q = 0; q < 8; ++q) {
      int idx = tid + 256 * q;
      int h = idx >> 5, e4 = idx & 31;
      float4 v = *(const float4*)(evnT + (size_t)(r * 64 + h) * 1024 + ebase + e4 * 4);
      *(float4*)&Et[h * 128 + e4 * 4] = v;
    }
  }
  __syncthreads();

  int sg = tid >> 4, egr = tid & 15;
  float acc[8][8];
#pragma unroll
  for (int i = 0; i < 8; ++i)
#pragma unroll
    for (int j = 0; j < 8; ++j) acc[i][j] = 0.f;

#pragma unroll 4
  for (int k = 0; k < 64; ++k) {
    float4 xa = *(const float4*)&Xt[k * 128 + sg * 8];
    float4 xb = *(const float4*)&Xt[k * 128 + sg * 8 + 4];
    float4 ea = *(const float4*)&Et[k * 128 + egr * 4];        // chunk A cols
    float4 eb = *(const float4*)&Et[k * 128 + 64 + egr * 4];   // chunk B cols
    const float* pa = (const float*)&xa;
    const float* pb = (const float*)&xb;
    const float* qa = (const float*)&ea;
    const float* qb = (const float*)&eb;
#pragma unroll
    for (int i = 0; i < 4; ++i)
#pragma unroll
      for (int j = 0; j < 4; ++j) {
        acc[i][j]         = fmaf(pa[i], qa[j], acc[i][j]);
        acc[i][j + 4]     = fmaf(pa[i], qb[j], acc[i][j + 4]);
        acc[i + 4][j]     = fmaf(pb[i], qa[j], acc[i + 4][j]);
        acc[i + 4][j + 4] = fmaf(pb[i], qb[j], acc[i + 4][j + 4]);
      }
  }

#pragma unroll
  for (int i = 0; i < 8; ++i) {
    float cA = expf(acc[i][0]) + expf(acc[i][1]) + expf(acc[i][2]) + expf(acc[i][3]);
    float cB = expf(acc[i][4]) + expf(acc[i][5]) + expf(acc[i][6]) + expf(acc[i][7]);
#pragma unroll
    for (int m = 1; m < 16; m <<= 1) {
      cA += __shfl_xor(cA, m);
      cB += __shfl_xor(cB, m);
    }
    int s = sg * 8 + i;
    if (egr == 0 && s < n) {
      C[(size_t)(off + s) * NCHUNK + et * 2]     = cA;
      C[(size_t)(off + s) * NCHUNK + et * 2 + 1] = cB;
    }
  }
}

// ---------------- pass2: chunk-level inverse-CDF, recompute 1 chunk --------
__global__ __launch_bounds__(256) void k_pass2(
    const float* __restrict__ evnT, const float* __restrict__ xunP,
    const float* __restrict__ C, const int2* __restrict__ top2,
    const int2* __restrict__ posmap, const float2* __restrict__ gwv,
    const float* __restrict__ rnd, float* __restrict__ out)
{
  int tid = threadIdx.x;
  int lane = tid & 63;
  int b = blockIdx.x * 4 + (tid >> 6);
  if (b >= B) return;
  int2 t2 = top2[b];
  t2.x &= 7; t2.y &= 7;
  int2 pm = posmap[b];
  pm.x = min(max(pm.x, 0), NPOS - 1);
  pm.y = min(max(pm.y, 0), NPOS - 1);
  float2 gw = gwv[b];
  float rv = rnd[b];

  // phase 1: redundant per-lane chunk CDF
  const float4* C04 = (const float4*)(C + (size_t)pm.x * NCHUNK);
  const float4* C14 = (const float4*)(C + (size_t)pm.y * NCHUNK);
  float c0[NCHUNK], c1[NCHUNK];
#pragma unroll
  for (int q = 0; q < 4; ++q) {
    float4 v0 = C04[q], v1 = C14[q];
    c0[q*4+0]=v0.x; c0[q*4+1]=v0.y; c0[q*4+2]=v0.z; c0[q*4+3]=v0.w;
    c1[q*4+0]=v1.x; c1[q*4+1]=v1.y; c1[q*4+2]=v1.z; c1[q*4+3]=v1.w;
  }
  float S0 = 0.f, S1 = 0.f;
#pragma unroll
  for (int j = 0; j < NCHUNK; ++j) { S0 += c0[j]; S1 += c1[j]; }
  float a0 = gw.x / S0, a1 = gw.y / S1;
  int cstar = -1; float prefix = 0.f; float run = 0.f;
#pragma unroll
  for (int j = 0; j < NCHUNK; ++j) {
    float nrun = run + (c0[j] * a0 + c1[j] * a1);
    if (cstar < 0 && nrun > rv) { cstar = j; prefix = run; }
    run = nrun;
  }
  float rtgt = rv;
  if (cstar < 0) { cstar = 0; prefix = 0.f; rtgt = -1.0f; }

  // phase 2: recompute chunk cstar; lane = local e
  float xu0 = xunP[(size_t)pm.x * H + lane];
  float xu1 = xunP[(size_t)pm.y * H + lane];
  const float* E0 = evnT + (size_t)t2.x * 64 * 1024 + cstar * CHUNK_E + lane;
  const float* E1 = evnT + (size_t)t2.y * 64 * 1024 + cstar * CHUNK_E + lane;
  float d0 = 0.f, d1 = 0.f;
#pragma unroll 16
  for (int h = 0; h < 64; ++h) {
    float w0 = __shfl(xu0, h);
    float w1 = __shfl(xu1, h);
    d0 = fmaf(E0[(size_t)h * 1024], w0, d0);
    d1 = fmaf(E1[(size_t)h * 1024], w1, d1);
  }
  float rea = expf(d0) * a0 + expf(d1) * a1;
  float sc = rea;
#pragma unroll
  for (int d = 1; d < 64; d <<= 1) {
    float o = __shfl_up(sc, d);
    if (lane >= d) sc += o;
  }
  float cum = prefix + sc;
  unsigned long long m2 = __ballot(cum > rtgt);
  int estar = (m2 == 0ull) ? 63 : (int)__builtin_ctzll(m2);
  float p = __shfl(rea, estar);
  if (lane == 0) {
    int sel = cstar * CHUNK_E + estar;
    out[b]     = (float)sel;
    out[B + b] = logf(p);
  }
}

// ---------------------------------------------------------------------------
extern "C" void kernel_launch(void* const* d_in, const int* in_sizes, int n_in,
                              void* d_out, int out_size, void* d_ws, size_t ws_size,
                              hipStream_t stream)
{
  (void)in_sizes; (void)n_in; (void)out_size; (void)ws_size;
  const float* x      = (const float*)d_in[0];
  const float* re     = (const float*)d_in[1];
  const float* rnd    = (const float*)d_in[2];
  const float* gate_w = (const float*)d_in[3];
  const float* gate_b = (const float*)d_in[4];
  const float* Uw     = (const float*)d_in[5];
  const float* Ub     = (const float*)d_in[6];
  const float* Vw     = (const float*)d_in[7];
  const float* Vb     = (const float*)d_in[8];
  char* ws = (char*)d_ws;
  int*    counts  = (int*)(ws + WS_COUNTS);
  int*    cursors = (int*)(ws + WS_CURSORS);
  float*  ps      = (float*)(ws + WS_PS);
  int2*   top2    = (int2*)(ws + WS_TOP2);
  float2* gwv     = (float2*)(ws + WS_GW);
  int2*   posmap  = (int2*)(ws + WS_POSMAP);
  int*    list    = (int*)(ws + WS_LIST);
  float*  evnT    = (float*)(ws + WS_EVN);
  float*  xunP    = (float*)(ws + WS_XUN);
  float*  Cc      = (float*)(ws + WS_C);
  float* out = (float*)d_out;

  hipMemsetAsync(ws, 0, 256, stream);
  k_gate   <<<256,  256, 0, stream>>>(x, gate_w, gate_b, top2, gwv, counts, ps);
  k_scatter<<<32,   256, 0, stream>>>(top2, counts, ps, cursors, list, posmap, out + 2 * B);
  k_proj   <<<2304, 256, 0, stream>>>(re, x, Vw, Vb, Uw, Ub, list, counts, evnT, xunP);
  k_pass1  <<<4096, 256, 0, stream>>>(evnT, xunP, counts, Cc);
  k_pass2  <<<2048, 256, 0, stream>>>(evnT, xunP, Cc, top2, posmap, gwv, rnd, out);
}

// Round 8
// 180.682 us; speedup vs baseline: 1.1771x; 1.1771x over previous
//
#include <hip/hip_runtime.h>
#include <math.h>

// Problem constants
#define B 8192
#define E 1024
#define D 384
#define H 64
#define R 8
#define NCHUNK 16
#define CHUNK_E 64
#define NPOS 16896          // 16384 + 8*64 per-router pad-to-64
#define NROW 25088          // 8192 evn rows + NPOS xun rows

// ws byte offsets (total 20,613,376 B)
#define WS_COUNTS   0u
#define WS_CURSORS  32u
#define WS_PS       64u
#define WS_TOP2     256u        // int2[B]
#define WS_GW       65792u      // float2[B]
#define WS_POSMAP   131328u     // int2[B]
#define WS_LIST     196864u     // int[NPOS]
#define WS_EVN      264448u     // float[8*64*1024] evnT[r][h][e]
#define WS_XUN      2361600u    // float[NPOS*64]   xunP[pos][h]
#define WS_C        6686976u    // float[NPOS*16]   C[pos][chunk]
#define WS_BUFA     7768320u    // float[NROW*64]   K-half partial 0
#define WS_BUFB     14190848u   // float[NROW*64]   K-half partial 1

// ---------------- gate: lane = (sample, router); LDS-transposed gate_w -----
__global__ __launch_bounds__(256) void k_gate(
    const float* __restrict__ x, const float* __restrict__ gate_w,
    const float* __restrict__ gate_b, int2* __restrict__ top2,
    float2* __restrict__ gwv, int* __restrict__ counts, float* __restrict__ ps)
{
  __shared__ __align__(16) float gwT[R * 388];
  __shared__ float psl[R];
  __shared__ int   cl[R];
  int tid = threadIdx.x;
  for (int idx = tid; idx < D * R; idx += 256) {
    int k = idx >> 3, r = idx & 7;
    gwT[r * 388 + k] = gate_w[idx];
  }
  if (tid < R) { psl[tid] = 0.f; cl[tid] = 0; }
  __syncthreads();

  int l = tid & 63;
  int r = tid & 7;
  int b = blockIdx.x * 32 + (tid >> 3);
  float acc = gate_b[r];
  const float4* x4 = (const float4*)(x + (size_t)b * D);
  const float*  gr = gwT + r * 388;
#pragma unroll 4
  for (int q = 0; q < 96; ++q) {
    float4 xv = x4[q];
    float4 gv = *(const float4*)&gr[q * 4];
    acc = fmaf(xv.x, gv.x, acc);
    acc = fmaf(xv.y, gv.y, acc);
    acc = fmaf(xv.z, gv.z, acc);
    acc = fmaf(xv.w, gv.w, acc);
  }
  float lv[R];
#pragma unroll
  for (int rr = 0; rr < R; ++rr) lv[rr] = __shfl(acc, (l & ~7) + rr);
  int i0 = 0; float v0 = lv[0];
#pragma unroll
  for (int rr = 1; rr < R; ++rr) if (lv[rr] > v0) { v0 = lv[rr]; i0 = rr; }
  int i1 = (i0 == 0) ? 1 : 0; float v1 = lv[i1];
#pragma unroll
  for (int rr = 0; rr < R; ++rr)
    if (rr != i0 && lv[rr] > v1) { v1 = lv[rr]; i1 = rr; }
  float se = 0.f;
#pragma unroll
  for (int rr = 0; rr < R; ++rr) se += expf(lv[rr] - v0);
  float p = expf(acc - v0) / se;
  if (r == 0) {
    float e10 = expf(v1 - v0);
    top2[b] = make_int2(i0, i1);
    gwv[b]  = make_float2(1.f / (1.f + e10), e10 / (1.f + e10));
  }
  float pa = p;
  int   ca = (r == i0 ? 1 : 0) + (r == i1 ? 1 : 0);
#pragma unroll
  for (int m = 8; m < 64; m <<= 1) {
    pa += __shfl_xor(pa, m);
    ca += __shfl_xor(ca, m);
  }
  if (l < 8) { atomicAdd(&psl[r], pa); atomicAdd(&cl[r], ca); }
  __syncthreads();
  if (tid < R) { atomicAdd(&ps[tid], psl[tid]); atomicAdd(&counts[tid], cl[tid]); }
}

// ---------------- scatter: per-router lists (padded-to-64 bases) + aux -----
__global__ __launch_bounds__(256) void k_scatter(
    const int2* __restrict__ top2, const int* __restrict__ counts,
    const float* __restrict__ ps, int* __restrict__ cursors,
    int* __restrict__ list, int2* __restrict__ posmap, float* __restrict__ out_aux)
{
  __shared__ int lc[R];
  __shared__ int lbase[R];
  __shared__ int offs[R];
  int tid = threadIdx.x;
  if (tid < R) lc[tid] = 0;
  __syncthreads();
  if (tid == 0) {
    int o = 0;
    for (int r2 = 0; r2 < R; ++r2) { offs[r2] = o; o += (min(counts[r2], B) + 63) & ~63; }
  }
  __syncthreads();
  int b = min(blockIdx.x * 256 + tid, B - 1);
  int2 t = top2[b];
  t.x &= 7; t.y &= 7;
  int p0 = atomicAdd(&lc[t.x], 1);
  int p1 = atomicAdd(&lc[t.y], 1);
  __syncthreads();
  if (tid < R) lbase[tid] = atomicAdd(&cursors[tid], lc[tid]);
  __syncthreads();
  int i0 = min(offs[t.x] + lbase[t.x] + p0, NPOS - 1);
  int i1 = min(offs[t.y] + lbase[t.y] + p1, NPOS - 1);
  list[i0] = b * 2 + 0;
  list[i1] = b * 2 + 1;
  posmap[b] = make_int2(i0, i1);
  if (blockIdx.x == 0 && tid == 0) {
    float s = 0.f;
    for (int r2 = 0; r2 < R; ++r2)
      s += (ps[r2] / (float)B) * ((float)min(counts[r2], B) / (float)B);
    out_aux[0] = (float)R * s * 0.05f;
  }
}

// ---------------- projgemm: unified (evn+xun) GEMM, K-split 2 --------------
// block = 64 rows x 64 h x 192 k (3 LDS stages of 64). grid 784 = 392 x 2.
// Rows [0,8192): evn (A = re[row&1023], W = Vw[row>>10]).
// Rows [8192,25088): xun (A = x[list[pos]>>1], W = Uw[r(pos)]).
// Per k-step: 2x ds_read_b128 (<=2-way) + 16 FMA. Partials -> bufA/bufB.
__global__ __launch_bounds__(256) void k_projgemm(
    const float* __restrict__ re, const float* __restrict__ x,
    const float* __restrict__ Vw, const float* __restrict__ Uw,
    const int* __restrict__ list, const int* __restrict__ counts,
    float* __restrict__ bufA, float* __restrict__ bufB)
{
  __shared__ __align__(16) float At[64 * 64];   // [k][row]
  __shared__ __align__(16) float Wt[64 * 64];   // [k][h]
  int tid = threadIdx.x;
  int bid = blockIdx.x;
  int tile = bid >> 1, ks = bid & 1;
  int row0 = tile * 64;

  const float* Wsrc;
  if (row0 < 8192) {
    Wsrc = Vw + (size_t)(row0 >> 10) * (D * H);
  } else {
    int pos0 = row0 - 8192;
    int r = 0, baseq = 0;
    for (int rr = 0; rr < R; ++rr) {
      if (pos0 >= baseq) r = rr;
      baseq += (min(counts[rr], B) + 63) & ~63;
    }
    Wsrc = Uw + (size_t)r * (D * H);
  }

  // staging roles: A: thread = (srow, k-quad); W: thread = (wk, wc)
  int srow = tid & 63, sq = tid >> 6;
  const float* arow;
  if (row0 < 8192) {
    arow = re + (size_t)((row0 + srow) & 1023) * D;
  } else {
    int pos = row0 - 8192 + srow;
    int gl = list[min(pos, NPOS - 1)];
    gl = min(max(gl, 0), 2 * B - 1);
    arow = x + (size_t)(gl >> 1) * D;
  }
  int wk = tid >> 2, wc = tid & 3;
  int rg = tid >> 4, hg = tid & 15;

  float acc[4][4];
#pragma unroll
  for (int i = 0; i < 4; ++i)
#pragma unroll
    for (int j = 0; j < 4; ++j) acc[i][j] = 0.f;

  for (int kt = 0; kt < 3; ++kt) {
    int kb = ks * 192 + kt * 64;
    __syncthreads();
#pragma unroll
    for (int q = 0; q < 4; ++q) {               // A -> At[k][row]
      float4 v = *(const float4*)&arow[kb + sq * 16 + q * 4];
      int k0 = sq * 16 + q * 4;
      At[(k0 + 0) * 64 + srow] = v.x;
      At[(k0 + 1) * 64 + srow] = v.y;
      At[(k0 + 2) * 64 + srow] = v.z;
      At[(k0 + 3) * 64 + srow] = v.w;
    }
    const float* wrow = Wsrc + (size_t)(kb + wk) * H;
#pragma unroll
    for (int q = 0; q < 4; ++q) {               // W -> Wt[k][h]
      float4 v = *(const float4*)&wrow[(wc * 4 + q) * 4];
      *(float4*)&Wt[wk * 64 + (wc * 4 + q) * 4] = v;
    }
    __syncthreads();
#pragma unroll 8
    for (int k = 0; k < 64; ++k) {
      float4 a4 = *(const float4*)&At[k * 64 + rg * 4];
      float4 w4 = *(const float4*)&Wt[k * 64 + hg * 4];
      const float* ap = (const float*)&a4;
      const float* wp = (const float*)&w4;
#pragma unroll
      for (int i = 0; i < 4; ++i)
#pragma unroll
        for (int j = 0; j < 4; ++j) acc[i][j] = fmaf(ap[i], wp[j], acc[i][j]);
    }
  }
  float* dst = (ks ? bufB : bufA) + (size_t)row0 * H;
#pragma unroll
  for (int i = 0; i < 4; ++i) {
    float4 o;
    o.x = acc[i][0]; o.y = acc[i][1]; o.z = acc[i][2]; o.w = acc[i][3];
    *(float4*)&dst[(rg * 4 + i) * H + hg * 4] = o;
  }
}

// ---------------- projfin: sum halves + bias + l2norm + layout -------------
// wave = 64 h-lanes x 8 rows; fixed summation order (deterministic).
__global__ __launch_bounds__(256) void k_projfin(
    const float* __restrict__ bufA, const float* __restrict__ bufB,
    const float* __restrict__ Vb, const float* __restrict__ Ub,
    const int* __restrict__ counts, float* __restrict__ evnT,
    float* __restrict__ xunP)
{
  int tid = threadIdx.x;
  int lane = tid & 63;
  int row0 = blockIdx.x * 32 + (tid >> 6) * 8;
  bool isE = row0 < 8192;
  int r = 0;
  if (isE) {
    r = row0 >> 10;
  } else {
    int pos0 = row0 - 8192;
    int baseq = 0;
    for (int rr = 0; rr < R; ++rr) {
      if (pos0 >= baseq) r = rr;
      baseq += (min(counts[rr], B) + 63) & ~63;
    }
  }
  float bias = isE ? Vb[r * H + lane] : Ub[r * H + lane];
#pragma unroll
  for (int i = 0; i < 8; ++i) {
    int row = row0 + i;
    float s = bufA[(size_t)row * H + lane] + bufB[(size_t)row * H + lane] + bias;
    float ss = s * s;
#pragma unroll
    for (int m = 1; m < 64; m <<= 1) ss += __shfl_xor(ss, m);
    float v = s / fmaxf(sqrtf(ss), 1e-12f);
    if (isE) evnT[(size_t)(r * 64 + lane) * 1024 + (row & 1023)] = v;
    else     xunP[(size_t)(row - 8192) * H + lane] = v;
  }
}

// ---------------- pass1: scores GEMM -> exp -> chunk sums ------------------
// tile 128 pos x 128 e (2 chunks); 8x8/thread; Et row-stride 132 (banks).
__global__ __launch_bounds__(256) void k_pass1(
    const float* __restrict__ evnT, const float* __restrict__ xunP,
    const int* __restrict__ counts, float* __restrict__ C)
{
  __shared__ __align__(16) float Xt[64 * 128];
  __shared__ __align__(16) float Et[64 * 132];
  __shared__ int cntL[R];
  int tid = threadIdx.x;
  if (tid < R) cntL[tid] = min(counts[tid], B);
  __syncthreads();

  int bid = blockIdx.x;
  int et    = bid & 7;
  int stile = (bid >> 3) & 63;
  int r     = bid >> 9;
  int cnt = cntL[r];
  if (cnt <= 0 || stile * 128 >= cnt) return;
  int off = 0;
  for (int rr = 0; rr < r; ++rr) off += (cntL[rr] + 63) & ~63;
  off += stile * 128;
  int n = min(128, cnt - stile * 128);
  int ebase = et * 128;

  {  // Xt: transpose-stage xunP rows [pos][h] -> [h][s]
    int row = tid >> 1;
    int rc  = min(row, n - 1);
    const float4* src = (const float4*)(xunP + (size_t)(off + rc) * H);
    int hq0 = (tid & 1) * 8;
#pragma unroll
    for (int q = 0; q < 8; ++q) {
      float4 v = src[hq0 + q];
      int h = (hq0 + q) * 4;
      Xt[(h + 0) * 128 + row] = v.x;
      Xt[(h + 1) * 128 + row] = v.y;
      Xt[(h + 2) * 128 + row] = v.z;
      Xt[(h + 3) * 128 + row] = v.w;
    }
  }
  {  // Et: direct copy of evnT [h][ebase..ebase+128)
#pragma unroll
    for (int q = 0; q < 8; ++q) {
      int idx = tid + 256 * q;
      int h = idx >> 5, e4 = idx & 31;
      float4 v = *(const float4*)(evnT + (size_t)(r * 64 + h) * 1024 + ebase + e4 * 4);
      *(float4*)&Et[h * 132 + e4 * 4] = v;
    }
  }
  __syncthreads();

  int sg = tid >> 4, egr = tid & 15;
  float acc[8][8];
#pragma unroll
  for (int i = 0; i < 8; ++i)
#pragma unroll
    for (int j = 0; j < 8; ++j) acc[i][j] = 0.f;

#pragma unroll 4
  for (int k = 0; k < 64; ++k) {
    float4 xa = *(const float4*)&Xt[k * 128 + sg * 8];
    float4 xb = *(const float4*)&Xt[k * 128 + sg * 8 + 4];
    float4 ea = *(const float4*)&Et[k * 132 + egr * 4];
    float4 eb = *(const float4*)&Et[k * 132 + 64 + egr * 4];
    const float* pa = (const float*)&xa;
    const float* pb = (const float*)&xb;
    const float* qa = (const float*)&ea;
    const float* qb = (const float*)&eb;
#pragma unroll
    for (int i = 0; i < 4; ++i)
#pragma unroll
      for (int j = 0; j < 4; ++j) {
        acc[i][j]         = fmaf(pa[i], qa[j], acc[i][j]);
        acc[i][j + 4]     = fmaf(pa[i], qb[j], acc[i][j + 4]);
        acc[i + 4][j]     = fmaf(pb[i], qa[j], acc[i + 4][j]);
        acc[i + 4][j + 4] = fmaf(pb[i], qb[j], acc[i + 4][j + 4]);
      }
  }

#pragma unroll
  for (int i = 0; i < 8; ++i) {
    float cA = expf(acc[i][0]) + expf(acc[i][1]) + expf(acc[i][2]) + expf(acc[i][3]);
    float cB = expf(acc[i][4]) + expf(acc[i][5]) + expf(acc[i][6]) + expf(acc[i][7]);
#pragma unroll
    for (int m = 1; m < 16; m <<= 1) {
      cA += __shfl_xor(cA, m);
      cB += __shfl_xor(cB, m);
    }
    int s = sg * 8 + i;
    if (egr == 0 && s < n) {
      C[(size_t)(off + s) * NCHUNK + et * 2]     = cA;
      C[(size_t)(off + s) * NCHUNK + et * 2 + 1] = cB;
    }
  }
}

// ---------------- pass2: chunk-level inverse-CDF, recompute 1 chunk --------
__global__ __launch_bounds__(256) void k_pass2(
    const float* __restrict__ evnT, const float* __restrict__ xunP,
    const float* __restrict__ C, const int2* __restrict__ top2,
    const int2* __restrict__ posmap, const float2* __restrict__ gwv,
    const float* __restrict__ rnd, float* __restrict__ out)
{
  int tid = threadIdx.x;
  int lane = tid & 63;
  int b = blockIdx.x * 4 + (tid >> 6);
  if (b >= B) return;
  int2 t2 = top2[b];
  t2.x &= 7; t2.y &= 7;
  int2 pm = posmap[b];
  pm.x = min(max(pm.x, 0), NPOS - 1);
  pm.y = min(max(pm.y, 0), NPOS - 1);
  float2 gw = gwv[b];
  float rv = rnd[b];

  // phase 1: redundant per-lane chunk CDF
  const float4* C04 = (const float4*)(C + (size_t)pm.x * NCHUNK);
  const float4* C14 = (const float4*)(C + (size_t)pm.y * NCHUNK);
  float c0[NCHUNK], c1[NCHUNK];
#pragma unroll
  for (int q = 0; q < 4; ++q) {
    float4 v0 = C04[q], v1 = C14[q];
    c0[q*4+0]=v0.x; c0[q*4+1]=v0.y; c0[q*4+2]=v0.z; c0[q*4+3]=v0.w;
    c1[q*4+0]=v1.x; c1[q*4+1]=v1.y; c1[q*4+2]=v1.z; c1[q*4+3]=v1.w;
  }
  float S0 = 0.f, S1 = 0.f;
#pragma unroll
  for (int j = 0; j < NCHUNK; ++j) { S0 += c0[j]; S1 += c1[j]; }
  float a0 = gw.x / S0, a1 = gw.y / S1;
  int cstar = -1; float prefix = 0.f; float run = 0.f;
#pragma unroll
  for (int j = 0; j < NCHUNK; ++j) {
    float nrun = run + (c0[j] * a0 + c1[j] * a1);
    if (cstar < 0 && nrun > rv) { cstar = j; prefix = run; }
    run = nrun;
  }
  float rtgt = rv;
  if (cstar < 0) { cstar = 0; prefix = 0.f; rtgt = -1.0f; }

  // phase 2: recompute chunk cstar; lane = local e
  float xu0 = xunP[(size_t)pm.x * H + lane];
  float xu1 = xunP[(size_t)pm.y * H + lane];
  const float* E0 = evnT + (size_t)t2.x * 64 * 1024 + cstar * CHUNK_E + lane;
  const float* E1 = evnT + (size_t)t2.y * 64 * 1024 + cstar * CHUNK_E + lane;
  float d0 = 0.f, d1 = 0.f;
#pragma unroll 16
  for (int h = 0; h < 64; ++h) {
    float w0 = __shfl(xu0, h);
    float w1 = __shfl(xu1, h);
    d0 = fmaf(E0[(size_t)h * 1024], w0, d0);
    d1 = fmaf(E1[(size_t)h * 1024], w1, d1);
  }
  float rea = expf(d0) * a0 + expf(d1) * a1;
  float sc = rea;
#pragma unroll
  for (int d = 1; d < 64; d <<= 1) {
    float o = __shfl_up(sc, d);
    if (lane >= d) sc += o;
  }
  float cum = prefix + sc;
  unsigned long long m2 = __ballot(cum > rtgt);
  int estar = (m2 == 0ull) ? 63 : (int)__builtin_ctzll(m2);
  float p = __shfl(rea, estar);
  if (lane == 0) {
    int sel = cstar * CHUNK_E + estar;
    out[b]     = (float)sel;
    out[B + b] = logf(p);
  }
}

// ---------------------------------------------------------------------------
extern "C" void kernel_launch(void* const* d_in, const int* in_sizes, int n_in,
                              void* d_out, int out_size, void* d_ws, size_t ws_size,
                              hipStream_t stream)
{
  (void)in_sizes; (void)n_in; (void)out_size; (void)ws_size;
  const float* x      = (const float*)d_in[0];
  const float* re     = (const float*)d_in[1];
  const float* rnd    = (const float*)d_in[2];
  const float* gate_w = (const float*)d_in[3];
  const float* gate_b = (const float*)d_in[4];
  const float* Uw     = (const float*)d_in[5];
  const float* Ub     = (const float*)d_in[6];
  const float* Vw     = (const float*)d_in[7];
  const float* Vb     = (const float*)d_in[8];
  char* ws = (char*)d_ws;
  int*    counts  = (int*)(ws + WS_COUNTS);
  int*    cursors = (int*)(ws + WS_CURSORS);
  float*  ps      = (float*)(ws + WS_PS);
  int2*   top2    = (int2*)(ws + WS_TOP2);
  float2* gwv     = (float2*)(ws + WS_GW);
  int2*   posmap  = (int2*)(ws + WS_POSMAP);
  int*    list    = (int*)(ws + WS_LIST);
  float*  evnT    = (float*)(ws + WS_EVN);
  float*  xunP    = (float*)(ws + WS_XUN);
  float*  Cc      = (float*)(ws + WS_C);
  float*  bufA    = (float*)(ws + WS_BUFA);
  float*  bufB    = (float*)(ws + WS_BUFB);
  float* out = (float*)d_out;

  hipMemsetAsync(ws, 0, 256, stream);
  k_gate    <<<256,  256, 0, stream>>>(x, gate_w, gate_b, top2, gwv, counts, ps);
  k_scatter <<<32,   256, 0, stream>>>(top2, counts, ps, cursors, list, posmap, out + 2 * B);
  k_projgemm<<<784,  256, 0, stream>>>(re, x, Vw, Uw, list, counts, bufA, bufB);
  k_projfin <<<784,  256, 0, stream>>>(bufA, bufB, Vb, Ub, counts, evnT, xunP);
  k_pass1   <<<4096, 256, 0, stream>>>(evnT, xunP, counts, Cc);
  k_pass2   <<<2048, 256, 0, stream>>>(evnT, xunP, Cc, top2, posmap, gwv, rnd, out);
}